// Round 6
// baseline (718.915 us; speedup 1.0000x reference)
//
#include <hip/hip_runtime.h>
#include <hip/hip_bf16.h>

typedef __bf16    bf16x8_t __attribute__((ext_vector_type(8)));
typedef float     f32x4_t  __attribute__((ext_vector_type(4)));
typedef short     s16x8_t  __attribute__((ext_vector_type(8)));
typedef unsigned  u32x4_t  __attribute__((ext_vector_type(4)));

#define S_LEN 2048
#define HDIM  64

#define K1_BQ    64
#define K1_BMSTR 264
#define K2_BQ    32
#define K2_BMSTR 264
#define PBSTR    264      // shorts per Pbuf row (528 B, 16B-aligned rows)
#define WS_RS_OFF 1024    // byte offset of rowsum array in d_ws

__device__ __forceinline__ short f2bf(float f) {
    return __builtin_bit_cast(short, (__bf16)f);
}
__device__ __forceinline__ float bf2f(short s) {
    return __builtin_bit_cast(float, ((unsigned)(unsigned short)s) << 16);
}
// 16 bytes -> 16 nonzero bits
__device__ __forceinline__ unsigned nzmask16(u32x4_t w) {
    unsigned n = 0;
    #pragma unroll
    for (int i = 0; i < 4; ++i) {
        const unsigned x = w[i];
        const unsigned t = (x & 0x7F7F7F7Fu) + 0x7F7F7F7Fu;
        const unsigned z = ((t | x) & 0x80808080u) >> 7;
        n |= ((z * 0x10204081u) >> 28) << (4 * i);
    }
    return n;
}
// 4 words -> 4 nonzero bits
__device__ __forceinline__ unsigned nzmask4w(u32x4_t w) {
    return (w[0] ? 1u : 0u) | (w[1] ? 2u : 0u) | (w[2] ? 4u : 0u) | (w[3] ? 8u : 0u);
}

#define PK8(lo, hi, out8) { s16x8_t _t; \
    _t[0]=f2bf((lo)[0]); _t[1]=f2bf((lo)[1]); _t[2]=f2bf((lo)[2]); _t[3]=f2bf((lo)[3]); \
    _t[4]=f2bf((hi)[0]); _t[5]=f2bf((hi)[1]); _t[6]=f2bf((hi)[2]); _t[7]=f2bf((hi)[3]); \
    (out8) = __builtin_bit_cast(bf16x8_t, _t); }

#define PKV(src, dst) { s16x8_t _t; \
    _t[0]=f2bf((src)[0]); _t[1]=f2bf((src)[1]); _t[2]=f2bf((src)[2]); _t[3]=f2bf((src)[3]); \
    _t[4]=f2bf((src)[4]); _t[5]=f2bf((src)[5]); _t[6]=f2bf((src)[6]); _t[7]=f2bf((src)[7]); \
    (dst) = __builtin_bit_cast(bf16x8_t, _t); }

__global__ void detect_mask(const unsigned char* __restrict__ M, int* __restrict__ flags) {
    __shared__ int cnt[4];
    if (threadIdx.x < 4) cnt[threadIdx.x] = 0;
    __syncthreads();
    int local[4] = {0, 0, 0, 0};
    for (int i = threadIdx.x; i < 16384; i += 256)
        if (M[i]) local[i & 3]++;
    #pragma unroll
    for (int c = 0; c < 4; ++c)
        if (local[c]) atomicAdd(&cnt[c], local[c]);
    __syncthreads();
    if (threadIdx.x == 0) {
        int stride;
        if (cnt[1] == 0 && cnt[2] == 0 && cnt[3] == 0)      stride = 4;  // int32
        else if (cnt[0] == 0 && cnt[1] == 0)                stride = 4;  // float32
        else                                                stride = 1;  // bool/int8
        flags[0] = stride;
    }
}

// ---------- Kernel 1: masked exp-rowsums only ----------
__global__ __launch_bounds__(512, 6)
void rowsum_k(const float* __restrict__ Q, const float* __restrict__ K,
              const unsigned char* __restrict__ M, const int* __restrict__ MF,
              float* __restrict__ RS)
{
    __shared__ unsigned char Bm[K1_BQ * K1_BMSTR];   // 64 rows x 2048 bits
    __shared__ float rsum_s[K1_BQ];

    const int tid = threadIdx.x;
    const int w    = tid >> 6;
    const int lane = tid & 63;
    const int col  = lane & 15;
    const int kg   = lane >> 4;
    const int mstride = MF[0];

    const int id   = blockIdx.x;            // 1024 = 32 b * 32 tiles
    const int slot = id >> 3;
    const int b    = ((slot >> 5) << 3) | (id & 7);
    const int q0   = (slot & 31) * K1_BQ;

    if (tid < K1_BQ) rsum_s[tid] = 0.f;

    {   // bitmask pack: thread t -> row t>>3, 256 elems at (t&7)*256
        const int row  = tid >> 3;
        const int segE = (tid & 7) * 256;
        unsigned long long bits[4] = {0ull, 0ull, 0ull, 0ull};
        if (mstride == 1) {
            const unsigned char* mp = M + (size_t)b * S_LEN * S_LEN
                                        + (size_t)(q0 + row) * S_LEN + segE;
            #pragma unroll
            for (int j = 0; j < 16; ++j)
                bits[j >> 2] |= (unsigned long long)nzmask16(*(const u32x4_t*)(mp + j * 16))
                                << (16 * (j & 3));
        } else {
            const unsigned* mp = (const unsigned*)M + (size_t)b * S_LEN * S_LEN
                                   + (size_t)(q0 + row) * S_LEN + segE;
            #pragma unroll
            for (int j = 0; j < 64; ++j)
                bits[j >> 4] |= (unsigned long long)nzmask4w(*(const u32x4_t*)(mp + j * 4))
                                << (4 * (j & 15));
        }
        unsigned long long* bp = (unsigned long long*)&Bm[row * K1_BMSTR + (tid & 7) * 32];
        bp[0] = bits[0]; bp[1] = bits[1]; bp[2] = bits[2]; bp[3] = bits[3];
    }

    // Q fragments: 4 rowgroups x 2 kk
    bf16x8_t af[4][2];
    #pragma unroll
    for (int m = 0; m < 4; ++m)
        #pragma unroll
        for (int kk = 0; kk < 2; ++kk) {
            const float* qp = Q + ((size_t)b * S_LEN + q0 + m * 16 + col) * HDIM + kk * 32 + kg * 8;
            const f32x4_t qa = *(const f32x4_t*)qp;
            const f32x4_t qb = *(const f32x4_t*)(qp + 4);
            PK8(qa, qb, af[m][kk]);
        }
    __syncthreads();

    float rs[4][4] = {{0.f,0.f,0.f,0.f},{0.f,0.f,0.f,0.f},{0.f,0.f,0.f,0.f},{0.f,0.f,0.f,0.f}};
    const float* Kb = K + (size_t)b * S_LEN * HDIM;
    #pragma unroll 2
    for (int f = 0; f < 16; ++f) {
        const int n0 = w * 256 + f * 16;
        const float* kp = Kb + (size_t)(n0 + col) * HDIM + kg * 8;
        const f32x4_t a0 = *(const f32x4_t*)kp,        a1 = *(const f32x4_t*)(kp + 4);
        const f32x4_t a2 = *(const f32x4_t*)(kp + 32), a3 = *(const f32x4_t*)(kp + 36);
        bf16x8_t b0, b1; PK8(a0, a1, b0); PK8(a2, a3, b1);
        #pragma unroll
        for (int m = 0; m < 4; ++m) {
            f32x4_t acc = {0.f, 0.f, 0.f, 0.f};
            acc = __builtin_amdgcn_mfma_f32_16x16x32_bf16(af[m][0], b0, acc, 0, 0, 0);
            acc = __builtin_amdgcn_mfma_f32_16x16x32_bf16(af[m][1], b1, acc, 0, 0, 0);
            #pragma unroll
            for (int r = 0; r < 4; ++r) {
                const int row = m * 16 + kg * 4 + r;
                const int ci  = n0 + col;
                const unsigned bb = Bm[row * K1_BMSTR + (ci >> 3)];
                if (!((bb >> (ci & 7)) & 1u))
                    rs[m][r] += __expf(acc[r] * 0.125f);
            }
        }
    }
    #pragma unroll
    for (int m = 0; m < 4; ++m)
        #pragma unroll
        for (int r = 0; r < 4; ++r) {
            float s = rs[m][r];
            s += __shfl_xor(s, 1); s += __shfl_xor(s, 2);
            s += __shfl_xor(s, 4); s += __shfl_xor(s, 8);
            if (col == 0) atomicAdd(&rsum_s[m * 16 + kg * 4 + r], s);
        }
    __syncthreads();
    if (tid < K1_BQ) RS[(size_t)b * S_LEN + q0 + tid] = rsum_s[tid];
}

// ---------- Kernel 2: streaming normalized attn + PV ----------
__global__ __launch_bounds__(512, 6)
void sdpa_stream(const float* __restrict__ Q, const float* __restrict__ K,
                 const float* __restrict__ V, const unsigned char* __restrict__ M,
                 const int* __restrict__ MF, const float* __restrict__ RS,
                 float* __restrict__ OUT)
{
    __shared__ short Pbuf[2][K2_BQ][PBSTR];        // 33792 B normalized bf16 p
    __shared__ unsigned char Bm[K2_BQ * K2_BMSTR]; // 8448 B
    __shared__ float Pvp[4][K2_BQ][17];            // 8704 B
    __shared__ float rinv_s[K2_BQ];

    const int tid = threadIdx.x;
    const int w    = tid >> 6;
    const int lane = tid & 63;
    const int col  = lane & 15;
    const int kg   = lane >> 4;
    const int mstride = MF[0];

    const int id   = blockIdx.x;            // 2048 = 32 b * 64 tiles
    const int slot = id >> 3;
    const int b    = ((slot >> 6) << 3) | (id & 7);
    const int q0   = (slot & 63) * K2_BQ;

    if (tid < K2_BQ) rinv_s[tid] = 1.0f / RS[(size_t)b * S_LEN + q0 + tid];

    {   // bitmask pack: thread t -> row t>>4, 128 elems at (t&15)*128
        const int row  = tid >> 4;
        const int segE = (tid & 15) * 128;
        unsigned long long bits[2] = {0ull, 0ull};
        if (mstride == 1) {
            const unsigned char* mp = M + (size_t)b * S_LEN * S_LEN
                                        + (size_t)(q0 + row) * S_LEN + segE;
            #pragma unroll
            for (int j = 0; j < 8; ++j)
                bits[j >> 2] |= (unsigned long long)nzmask16(*(const u32x4_t*)(mp + j * 16))
                                << (16 * (j & 3));
        } else {
            const unsigned* mp = (const unsigned*)M + (size_t)b * S_LEN * S_LEN
                                   + (size_t)(q0 + row) * S_LEN + segE;
            #pragma unroll
            for (int j = 0; j < 32; ++j)
                bits[j >> 4] |= (unsigned long long)nzmask4w(*(const u32x4_t*)(mp + j * 4))
                                << (4 * (j & 15));
        }
        unsigned long long* bp = (unsigned long long*)&Bm[row * K2_BMSTR + (tid & 15) * 16];
        bp[0] = bits[0]; bp[1] = bits[1];
    }

    // Q fragments: 2 rowgroups x 2 kk (same for every wave)
    bf16x8_t afrag[2][2];
    #pragma unroll
    for (int m = 0; m < 2; ++m)
        #pragma unroll
        for (int kk = 0; kk < 2; ++kk) {
            const float* qp = Q + ((size_t)b * S_LEN + q0 + m * 16 + col) * HDIM + kk * 32 + kg * 8;
            const f32x4_t qa = *(const f32x4_t*)qp;
            const f32x4_t qb = *(const f32x4_t*)(qp + 4);
            PK8(qa, qb, afrag[m][kk]);
        }

    const float* Kb = K + (size_t)b * S_LEN * HDIM;
    const float* Vb = V + (size_t)b * S_LEN * HDIM;
    float* attn = OUT + (size_t)32 * S_LEN * HDIM + ((size_t)b * S_LEN + q0) * S_LEN;
    const int cgv = (w & 3) * 16;    // PV ctx col group
    const int klb = (w >> 2) * 128;  // PV k-slice base within chunk

#define STAGE(CH, DB) do { \
    const int nb_ = (CH) * 256 + w * 32; \
    const float* kp0_ = Kb + (size_t)(nb_ + col) * HDIM + kg * 8; \
    const f32x4_t a0_ = *(const f32x4_t*)kp0_,        a1_ = *(const f32x4_t*)(kp0_ + 4); \
    const f32x4_t a2_ = *(const f32x4_t*)(kp0_ + 32), a3_ = *(const f32x4_t*)(kp0_ + 36); \
    const float* kp1_ = Kb + (size_t)(nb_ + 16 + col) * HDIM + kg * 8; \
    const f32x4_t c0_ = *(const f32x4_t*)kp1_,        c1_ = *(const f32x4_t*)(kp1_ + 4); \
    const f32x4_t c2_ = *(const f32x4_t*)(kp1_ + 32), c3_ = *(const f32x4_t*)(kp1_ + 36); \
    bf16x8_t b0_, b1_; PK8(a0_, a1_, b0_); PK8(a2_, a3_, b1_); \
    f32x4_t s00_ = {0.f,0.f,0.f,0.f}, s10_ = {0.f,0.f,0.f,0.f}; \
    s00_ = __builtin_amdgcn_mfma_f32_16x16x32_bf16(afrag[0][0], b0_, s00_, 0,0,0); \
    s00_ = __builtin_amdgcn_mfma_f32_16x16x32_bf16(afrag[0][1], b1_, s00_, 0,0,0); \
    s10_ = __builtin_amdgcn_mfma_f32_16x16x32_bf16(afrag[1][0], b0_, s10_, 0,0,0); \
    s10_ = __builtin_amdgcn_mfma_f32_16x16x32_bf16(afrag[1][1], b1_, s10_, 0,0,0); \
    bf16x8_t d0_, d1_; PK8(c0_, c1_, d0_); PK8(c2_, c3_, d1_); \
    f32x4_t s01_ = {0.f,0.f,0.f,0.f}, s11_ = {0.f,0.f,0.f,0.f}; \
    s01_ = __builtin_amdgcn_mfma_f32_16x16x32_bf16(afrag[0][0], d0_, s01_, 0,0,0); \
    s01_ = __builtin_amdgcn_mfma_f32_16x16x32_bf16(afrag[0][1], d1_, s01_, 0,0,0); \
    s11_ = __builtin_amdgcn_mfma_f32_16x16x32_bf16(afrag[1][0], d0_, s11_, 0,0,0); \
    s11_ = __builtin_amdgcn_mfma_f32_16x16x32_bf16(afrag[1][1], d1_, s11_, 0,0,0); \
    _Pragma("unroll") \
    for (int m_ = 0; m_ < 2; ++m_) { \
        const f32x4_t e0_ = m_ ? s10_ : s00_; \
        const f32x4_t e1_ = m_ ? s11_ : s01_; \
        _Pragma("unroll") \
        for (int r_ = 0; r_ < 4; ++r_) { \
            const int row_ = m_ * 16 + kg * 4 + r_; \
            const float ri_ = rinv_s[row_]; \
            const int cg0_ = w * 32 + col; \
            const int ci0_ = (CH) * 256 + cg0_; \
            const unsigned bb0_ = Bm[row_ * K2_BMSTR + (ci0_ >> 3)]; \
            const float p0_ = ((bb0_ >> (ci0_ & 7)) & 1u) ? 0.f : __expf(e0_[r_] * 0.125f) * ri_; \
            Pbuf[DB][row_][cg0_] = f2bf(p0_); \
            const int cg1_ = cg0_ + 16; \
            const int ci1_ = ci0_ + 16; \
            const unsigned bb1_ = Bm[row_ * K2_BMSTR + (ci1_ >> 3)]; \
            const float p1_ = ((bb1_ >> (ci1_ & 7)) & 1u) ? 0.f : __expf(e1_[r_] * 0.125f) * ri_; \
            Pbuf[DB][row_][cg1_] = f2bf(p1_); \
        } \
    } \
} while (0)

#define LOADV(KS, dst) { \
    const float* vp_ = Vb + (size_t)((CH_C) * 256 + klb + (KS) * 32 + kg * 8) * HDIM + cgv + col; \
    dst[0] = vp_[0];        dst[1] = vp_[HDIM];     dst[2] = vp_[2 * HDIM]; dst[3] = vp_[3 * HDIM]; \
    dst[4] = vp_[4 * HDIM]; dst[5] = vp_[5 * HDIM]; dst[6] = vp_[6 * HDIM]; dst[7] = vp_[7 * HDIM]; }

    f32x4_t cacc[2] = {{0.f,0.f,0.f,0.f},{0.f,0.f,0.f,0.f}};

#define CONSUME(CH, DB) do { \
    const int CH_C = (CH); \
    float vr0_[8], vr1_[8]; \
    LOADV(0, vr0_); LOADV(1, vr1_); \
    { /* attn stream-out of this chunk (already normalized) */ \
        const int row_ = tid >> 4; \
        const int cs_  = (tid & 15) * 16; \
        const s16x8_t pv0_ = *(const s16x8_t*)&Pbuf[DB][row_][cs_]; \
        const s16x8_t pv1_ = *(const s16x8_t*)&Pbuf[DB][row_][cs_ + 8]; \
        f32x4_t o0_, o1_, o2_, o3_; \
        o0_[0]=bf2f(pv0_[0]); o0_[1]=bf2f(pv0_[1]); o0_[2]=bf2f(pv0_[2]); o0_[3]=bf2f(pv0_[3]); \
        o1_[0]=bf2f(pv0_[4]); o1_[1]=bf2f(pv0_[5]); o1_[2]=bf2f(pv0_[6]); o1_[3]=bf2f(pv0_[7]); \
        o2_[0]=bf2f(pv1_[0]); o2_[1]=bf2f(pv1_[1]); o2_[2]=bf2f(pv1_[2]); o2_[3]=bf2f(pv1_[3]); \
        o3_[0]=bf2f(pv1_[4]); o3_[1]=bf2f(pv1_[5]); o3_[2]=bf2f(pv1_[6]); o3_[3]=bf2f(pv1_[7]); \
        float* op_ = attn + (size_t)row_ * S_LEN + CH_C * 256 + cs_; \
        *(f32x4_t*)op_        = o0_; *(f32x4_t*)(op_ + 4)  = o1_; \
        *(f32x4_t*)(op_ + 8)  = o2_; *(f32x4_t*)(op_ + 12) = o3_; \
    } \
    bf16x8_t vb0_, vb1_; PKV(vr0_, vb0_); PKV(vr1_, vb1_); \
    LOADV(2, vr0_); LOADV(3, vr1_); \
    _Pragma("unroll") \
    for (int m_ = 0; m_ < 2; ++m_) { \
        const bf16x8_t pa0_ = *(const bf16x8_t*)&Pbuf[DB][m_ * 16 + col][klb + kg * 8]; \
        const bf16x8_t pa1_ = *(const bf16x8_t*)&Pbuf[DB][m_ * 16 + col][klb + 32 + kg * 8]; \
        cacc[m_] = __builtin_amdgcn_mfma_f32_16x16x32_bf16(pa0_, vb0_, cacc[m_], 0,0,0); \
        cacc[m_] = __builtin_amdgcn_mfma_f32_16x16x32_bf16(pa1_, vb1_, cacc[m_], 0,0,0); \
    } \
    PKV(vr0_, vb0_); PKV(vr1_, vb1_); \
    _Pragma("unroll") \
    for (int m_ = 0; m_ < 2; ++m_) { \
        const bf16x8_t pa2_ = *(const bf16x8_t*)&Pbuf[DB][m_ * 16 + col][klb + 64 + kg * 8]; \
        const bf16x8_t pa3_ = *(const bf16x8_t*)&Pbuf[DB][m_ * 16 + col][klb + 96 + kg * 8]; \
        cacc[m_] = __builtin_amdgcn_mfma_f32_16x16x32_bf16(pa2_, vb0_, cacc[m_], 0,0,0); \
        cacc[m_] = __builtin_amdgcn_mfma_f32_16x16x32_bf16(pa3_, vb1_, cacc[m_], 0,0,0); \
    } \
} while (0)

    __syncthreads();     // Bm + rinv ready
    STAGE(0, 0);
    __syncthreads();
    for (int ch = 0; ch < 8; ++ch) {
        if (ch < 7) STAGE(ch + 1, (ch + 1) & 1);
        CONSUME(ch, ch & 1);
        __syncthreads();
    }

    // ctx reduction across k-halves and store
    if (w >= 4) {
        #pragma unroll
        for (int m = 0; m < 2; ++m)
            #pragma unroll
            for (int r = 0; r < 4; ++r)
                Pvp[w - 4][m * 16 + kg * 4 + r][col] = cacc[m][r];
    }
    __syncthreads();
    if (w < 4) {
        #pragma unroll
        for (int m = 0; m < 2; ++m)
            #pragma unroll
            for (int r = 0; r < 4; ++r) {
                const int row = m * 16 + kg * 4 + r;
                OUT[((size_t)b * S_LEN + q0 + row) * HDIM + w * 16 + col]
                    = cacc[m][r] + Pvp[w][row][col];
            }
    }
#undef STAGE
#undef LOADV
#undef CONSUME
}

extern "C" void kernel_launch(void* const* d_in, const int* in_sizes, int n_in,
                              void* d_out, int out_size, void* d_ws, size_t ws_size,
                              hipStream_t stream)
{
    const float* q = (const float*)d_in[0];
    const float* k = (const float*)d_in[1];
    const float* v = (const float*)d_in[2];
    const unsigned char* mask = (const unsigned char*)d_in[3];
    int*   mflags = (int*)d_ws;
    float* rs_ws  = (float*)((char*)d_ws + WS_RS_OFF);   // 32*2048 f32 = 256 KB
    float* out = (float*)d_out;

    detect_mask<<<dim3(1), dim3(256), 0, stream>>>(mask, mflags);
    rowsum_k<<<dim3(1024), dim3(512), 0, stream>>>(q, k, mask, mflags, rs_ws);
    sdpa_stream<<<dim3(2048), dim3(512), 0, stream>>>(q, k, v, mask, mflags, rs_ws, out);
}

// Round 8
// 441.254 us; speedup vs baseline: 1.6293x; 1.6293x over previous
//
#include <hip/hip_runtime.h>
#include <hip/hip_bf16.h>

typedef __bf16    bf16x8_t __attribute__((ext_vector_type(8)));
typedef float     f32x4_t  __attribute__((ext_vector_type(4)));
typedef short     s16x4_t  __attribute__((ext_vector_type(4)));
typedef short     s16x8_t  __attribute__((ext_vector_type(8)));
typedef unsigned  u32x4_t  __attribute__((ext_vector_type(4)));

#define S_LEN 2048
#define HDIM  64
#define BQ    32
#define NTHREADS 512
#define PSTR_B 4112       // P row byte stride (2056 bf16); stride%128B=16 -> rows
                          // offset by 4 banks: 16-row b128 reads spread evenly,
                          // no swizzle needed (r7 post-mortem: XOR swizzle with
                          // non-256-aligned stride was NON-BIJECTIVE -> corruption)
#define BMSTR 264

__device__ __forceinline__ short f2bf(float f) {
    return __builtin_bit_cast(short, (__bf16)f);
}
__device__ __forceinline__ float bf2f(short s) {
    return __builtin_bit_cast(float, ((unsigned)(unsigned short)s) << 16);
}
__device__ __forceinline__ short* pelem(short* P, int row, int e) {
    return (short*)((char*)P + (unsigned)row * PSTR_B + (unsigned)e * 2u);
}
__device__ __forceinline__ const short* pelemc(const short* P, int row, int e) {
    return pelem(const_cast<short*>(P), row, e);
}
__device__ __forceinline__ unsigned nzmask16(u32x4_t w) {
    unsigned n = 0;
    #pragma unroll
    for (int i = 0; i < 4; ++i) {
        const unsigned x = w[i];
        const unsigned t = (x & 0x7F7F7F7Fu) + 0x7F7F7F7Fu;
        const unsigned z = ((t | x) & 0x80808080u) >> 7;
        n |= ((z * 0x10204081u) >> 28) << (4 * i);
    }
    return n;
}
__device__ __forceinline__ unsigned nzmask4w(u32x4_t w) {
    return (w[0] ? 1u : 0u) | (w[1] ? 2u : 0u) | (w[2] ? 4u : 0u) | (w[3] ? 8u : 0u);
}

#define PK8(lo, hi, out8) { s16x8_t _t; \
    _t[0]=f2bf((lo)[0]); _t[1]=f2bf((lo)[1]); _t[2]=f2bf((lo)[2]); _t[3]=f2bf((lo)[3]); \
    _t[4]=f2bf((hi)[0]); _t[5]=f2bf((hi)[1]); _t[6]=f2bf((hi)[2]); _t[7]=f2bf((hi)[3]); \
    (out8) = __builtin_bit_cast(bf16x8_t, _t); }
#define PKV(src, dst) { s16x8_t _t; \
    _t[0]=f2bf((src)[0]); _t[1]=f2bf((src)[1]); _t[2]=f2bf((src)[2]); _t[3]=f2bf((src)[3]); \
    _t[4]=f2bf((src)[4]); _t[5]=f2bf((src)[5]); _t[6]=f2bf((src)[6]); _t[7]=f2bf((src)[7]); \
    (dst) = __builtin_bit_cast(bf16x8_t, _t); }

__global__ void detect_mask(const unsigned char* __restrict__ M, int* __restrict__ flags) {
    __shared__ int cnt[4];
    if (threadIdx.x < 4) cnt[threadIdx.x] = 0;
    __syncthreads();
    int local[4] = {0, 0, 0, 0};
    for (int i = threadIdx.x; i < 16384; i += 256)
        if (M[i]) local[i & 3]++;
    #pragma unroll
    for (int c = 0; c < 4; ++c)
        if (local[c]) atomicAdd(&cnt[c], local[c]);
    __syncthreads();
    if (threadIdx.x == 0) {
        int stride;
        if (cnt[1] == 0 && cnt[2] == 0 && cnt[3] == 0)      stride = 4;  // int32
        else if (cnt[0] == 0 && cnt[1] == 0)                stride = 4;  // float32
        else                                                stride = 1;  // bool/int8
        flags[0] = stride;
    }
}

// One fused kernel. Register-rich (launch_bounds min=2 -> up to 256 VGPR),
// 1 block/CU (LDS ~149KB), phase-2 is barrier-free with deep per-wave MLP.
__global__ __launch_bounds__(NTHREADS, 2)
void sdpa_one(const float* __restrict__ Q, const float* __restrict__ K,
              const float* __restrict__ V, const unsigned char* __restrict__ M,
              const int* __restrict__ MF, float* __restrict__ OUT)
{
    __shared__ short Plds[BQ * (PSTR_B / 2)];      // 131584 B unnormalized exp, bf16
    __shared__ unsigned char Bm[BQ * BMSTR];       // 8448 B mask bits
    __shared__ float Pvp[4][BQ][17];               // 8704 B PV k-half partials
    __shared__ float rowsum[BQ];
    __shared__ float rinv_s[BQ];

    const int tid  = threadIdx.x;
    const int w    = tid >> 6;
    const int lane = tid & 63;
    const int col  = lane & 15;
    const int kg   = lane >> 4;
    const int mstride = MF[0];

    // 2048 blocks = 8 xcd * 256 slots (bijective, nwg%8==0)
    const int id   = blockIdx.x;
    const int slot = id >> 3;
    const int b    = ((slot >> 6) << 3) | (id & 7);
    const int q0   = (slot & 63) * BQ;

    float* attn_out = OUT + (size_t)32 * S_LEN * HDIM;

    if (tid < BQ) rowsum[tid] = 0.f;

    {   // ---- mask tile -> 1-bit/elem LDS bitmask (single coalesced pass)
        const int row  = tid >> 4;            // 0..31
        const int segE = (tid & 15) * 128;
        unsigned long long bits[2] = {0ull, 0ull};
        if (mstride == 1) {
            const unsigned char* mp = M + (size_t)b * S_LEN * S_LEN
                                        + (size_t)(q0 + row) * S_LEN + segE;
            #pragma unroll
            for (int j = 0; j < 8; ++j)
                bits[j >> 2] |= (unsigned long long)nzmask16(*(const u32x4_t*)(mp + j * 16))
                                << (16 * (j & 3));
        } else {
            const unsigned* mp = (const unsigned*)M + (size_t)b * S_LEN * S_LEN
                                   + (size_t)(q0 + row) * S_LEN + segE;
            #pragma unroll
            for (int j = 0; j < 32; ++j)
                bits[j >> 4] |= (unsigned long long)nzmask4w(*(const u32x4_t*)(mp + j * 4))
                                << (4 * (j & 15));
        }
        unsigned long long* bp = (unsigned long long*)&Bm[row * BMSTR + (tid & 15) * 16];
        bp[0] = bits[0]; bp[1] = bits[1];
    }

    // Q fragments (each wave loads all 32 rows: L1-served, tiny)
    bf16x8_t af[2][2];
    #pragma unroll
    for (int m = 0; m < 2; ++m)
        #pragma unroll
        for (int kk = 0; kk < 2; ++kk) {
            const float* qp = Q + ((size_t)b * S_LEN + q0 + m * 16 + col) * HDIM + kk * 32 + kg * 8;
            const f32x4_t qa = *(const f32x4_t*)qp;
            const f32x4_t qb = *(const f32x4_t*)(qp + 4);
            PK8(qa, qb, af[m][kk]);
        }
    __syncthreads();

    // ---- Phase 1: QK^T/8 -> exp -> mask -> Plds (unnormalized); reg rowsums
    float rs[2][4] = {{0.f,0.f,0.f,0.f},{0.f,0.f,0.f,0.f}};
    {
        const float* Kb = K + (size_t)b * S_LEN * HDIM;
        f32x4_t A0,B0,C0,D0, A1,B1,C1,D1;
#define LDK(f, AX,BX,CX,DX) { \
    const float* kp = Kb + (size_t)(w * 256 + (f) * 16 + col) * HDIM + kg * 8; \
    AX = *(const f32x4_t*)kp;        BX = *(const f32x4_t*)(kp + 4); \
    CX = *(const f32x4_t*)(kp + 32); DX = *(const f32x4_t*)(kp + 36); }
#define STEP(f, AX,BX,CX,DX, PF, fp) { \
    bf16x8_t kb0, kb1; PK8(AX, BX, kb0); PK8(CX, DX, kb1); \
    if (PF) LDK(fp, AX,BX,CX,DX); \
    f32x4_t acc0 = {0.f,0.f,0.f,0.f}, acc1 = {0.f,0.f,0.f,0.f}; \
    acc0 = __builtin_amdgcn_mfma_f32_16x16x32_bf16(af[0][0], kb0, acc0, 0,0,0); \
    acc0 = __builtin_amdgcn_mfma_f32_16x16x32_bf16(af[0][1], kb1, acc0, 0,0,0); \
    acc1 = __builtin_amdgcn_mfma_f32_16x16x32_bf16(af[1][0], kb0, acc1, 0,0,0); \
    acc1 = __builtin_amdgcn_mfma_f32_16x16x32_bf16(af[1][1], kb1, acc1, 0,0,0); \
    const int c = w * 256 + (f) * 16 + col; \
    _Pragma("unroll") \
    for (int r = 0; r < 4; ++r) { \
        const int row0 = kg * 4 + r; \
        const unsigned b0m = Bm[row0 * BMSTR + (c >> 3)]; \
        const float p0 = ((b0m >> (c & 7)) & 1u) ? 0.f : __expf(acc0[r] * 0.125f); \
        rs[0][r] += p0; \
        *pelem(Plds, row0, c) = f2bf(p0); \
        const int row1 = 16 + kg * 4 + r; \
        const unsigned b1m = Bm[row1 * BMSTR + (c >> 3)]; \
        const float p1 = ((b1m >> (c & 7)) & 1u) ? 0.f : __expf(acc1[r] * 0.125f); \
        rs[1][r] += p1; \
        *pelem(Plds, row1, c) = f2bf(p1); \
    } }
        LDK(0, A0,B0,C0,D0);
        LDK(1, A1,B1,C1,D1);
        #pragma unroll
        for (int ff = 0; ff < 16; ff += 2) {
            STEP(ff,     A0,B0,C0,D0, (ff + 2 < 16), ff + 2);
            STEP(ff + 1, A1,B1,C1,D1, (ff + 3 < 16), ff + 3);
        }
#undef LDK
#undef STEP
    }
    #pragma unroll
    for (int m = 0; m < 2; ++m)
        #pragma unroll
        for (int r = 0; r < 4; ++r) {
            float s = rs[m][r];
            s += __shfl_xor(s, 1); s += __shfl_xor(s, 2);
            s += __shfl_xor(s, 4); s += __shfl_xor(s, 8);
            if (col == 0) atomicAdd(&rowsum[m * 16 + kg * 4 + r], s);
        }
    __syncthreads();
    if (tid < BQ) rinv_s[tid] = 1.0f / rowsum[tid];
    __syncthreads();

    // ---- Phase 2 (barrier-free): per-wave PV (k-half x col-group) with
    // attn store bursts interleaved. Stores are never drained mid-loop.
    const int hb    = (w & 3) * 16;
    const int kbase = (w >> 2) * 1024;
    const float* Vb = V + (size_t)b * S_LEN * HDIM;

    const int srow = w * 4 + (lane >> 4);          // this lane's attn store row
    const float my_rinv = rinv_s[srow];
    float* abp = attn_out + ((size_t)b * S_LEN + q0 + srow) * S_LEN + (lane & 15) * 4;

    f32x4_t cacc0 = {0.f,0.f,0.f,0.f}, cacc1 = {0.f,0.f,0.f,0.f};
    float vr0[8], vr1[8];
#define LOADV(kc, dst) { \
    const float* vp = Vb + (size_t)(kbase + (kc) * 32 + kg * 8) * HDIM + hb + col; \
    dst[0] = vp[0];        dst[1] = vp[HDIM];     dst[2] = vp[2*HDIM]; dst[3] = vp[3*HDIM]; \
    dst[4] = vp[4*HDIM];   dst[5] = vp[5*HDIM];   dst[6] = vp[6*HDIM]; dst[7] = vp[7*HDIM]; }
#define PVSTEP(kc, vsrc) { \
    bf16x8_t vbf; PKV(vsrc, vbf); \
    const int ke = kbase + (kc) * 32 + kg * 8; \
    const bf16x8_t pa0 = *(const bf16x8_t*)pelemc(Plds, col,      ke); \
    const bf16x8_t pa1 = *(const bf16x8_t*)pelemc(Plds, 16 + col, ke); \
    cacc0 = __builtin_amdgcn_mfma_f32_16x16x32_bf16(pa0, vbf, cacc0, 0,0,0); \
    cacc1 = __builtin_amdgcn_mfma_f32_16x16x32_bf16(pa1, vbf, cacc1, 0,0,0); }
#define BURST(s) { _Pragma("unroll") for (int c4 = 0; c4 < 4; ++c4) { \
    const int cb = (s) * 256 + c4 * 64 + (lane & 15) * 4; \
    const s16x4_t pv = *(const s16x4_t*)pelemc(Plds, srow, cb); \
    f32x4_t o; \
    o[0] = bf2f(pv[0]) * my_rinv; o[1] = bf2f(pv[1]) * my_rinv; \
    o[2] = bf2f(pv[2]) * my_rinv; o[3] = bf2f(pv[3]) * my_rinv; \
    *(f32x4_t*)(abp + (s) * 256 + c4 * 64) = o; } }

    LOADV(0, vr0);
    #pragma unroll
    for (int kc2 = 0; kc2 < 16; ++kc2) {
        LOADV(2 * kc2 + 1, vr1);
        if ((kc2 & 1) == 0) BURST(kc2 >> 1);
        PVSTEP(2 * kc2, vr0);
        if (kc2 < 15) LOADV(2 * kc2 + 2, vr0);
        PVSTEP(2 * kc2 + 1, vr1);
    }
#undef LOADV
#undef PVSTEP
#undef BURST

    // ---- ctx: reduce k-halves, normalize, store
    if (w >= 4) {
        #pragma unroll
        for (int r = 0; r < 4; ++r) {
            Pvp[w - 4][kg * 4 + r][col]      = cacc0[r];
            Pvp[w - 4][16 + kg * 4 + r][col] = cacc1[r];
        }
    }
    __syncthreads();
    if (w < 4) {
        #pragma unroll
        for (int r = 0; r < 4; ++r) {
            const int row0 = kg * 4 + r;
            const int row1 = 16 + kg * 4 + r;
            OUT[((size_t)b * S_LEN + q0 + row0) * HDIM + hb + col]
                = (cacc0[r] + Pvp[w][row0][col]) * rinv_s[row0];
            OUT[((size_t)b * S_LEN + q0 + row1) * HDIM + hb + col]
                = (cacc1[r] + Pvp[w][row1][col]) * rinv_s[row1];
        }
    }
}

extern "C" void kernel_launch(void* const* d_in, const int* in_sizes, int n_in,
                              void* d_out, int out_size, void* d_ws, size_t ws_size,
                              hipStream_t stream)
{
    const float* q = (const float*)d_in[0];
    const float* k = (const float*)d_in[1];
    const float* v = (const float*)d_in[2];
    const unsigned char* mask = (const unsigned char*)d_in[3];
    int* mflags = (int*)d_ws;
    float* out = (float*)d_out;
    detect_mask<<<dim3(1), dim3(256), 0, stream>>>(mask, mflags);
    sdpa_one<<<dim3(2048), dim3(NTHREADS), 0, stream>>>(q, k, v, mask, mflags, out);
}